// Round 7
// baseline (823.011 us; speedup 1.0000x reference)
//
#include <hip/hip_runtime.h>
#include <hip/hip_bf16.h>

typedef __bf16 bf16x8 __attribute__((ext_vector_type(8)));
typedef float f32x4 __attribute__((ext_vector_type(4)));

__device__ __forceinline__ void gload16(const void* g, void* l) {
  __builtin_amdgcn_global_load_lds(
      (const __attribute__((address_space(1))) void*)g,
      (__attribute__((address_space(3))) void*)l, 16, 0, 0);
}

__device__ __forceinline__ unsigned short f2bf(float f) {
  __hip_bfloat16 h = __float2bfloat16(f);
  union { __hip_bfloat16 h; unsigned short u; } c;
  c.h = h;
  return c.u;
}

__device__ __forceinline__ void fwht16(float v[16]) {
#pragma unroll
  for (int s = 1; s < 16; s <<= 1) {
#pragma unroll
    for (int i = 0; i < 16; i++) {
      if ((i & s) == 0) {
        float a = v[i], b = v[i | s];
        v[i] = a + b;
        v[i | s] = a - b;
      }
    }
  }
}

// ---------------- FWHT #1: h1 = bf16( fwht(x*SU) / 2048 ) ----------------
__global__ __launch_bounds__(256) void fwht1_kernel(
    const float* __restrict__ x, const float* __restrict__ SU,
    unsigned short* __restrict__ H1) {
  __shared__ float lds[256 * 17];
  const int t = threadIdx.x;
  const size_t row = blockIdx.x;
  const float* xr = x + row * 4096;
  float v[16];
#pragma unroll
  for (int n2 = 0; n2 < 16; n2++) {
    int n = n2 * 256 + t;
    v[n2] = xr[n] * SU[n];
  }
  fwht16(v);
  const int n1 = t >> 4, n0 = t & 15;
#pragma unroll
  for (int j2 = 0; j2 < 16; j2++) lds[(j2 * 16 + n1) * 17 + n0] = v[j2];
  __syncthreads();
#pragma unroll
  for (int k = 0; k < 16; k++) v[k] = lds[((t >> 4) * 16 + k) * 17 + (t & 15)];
  fwht16(v);
#pragma unroll
  for (int k = 0; k < 16; k++) lds[((t >> 4) * 16 + k) * 17 + (t & 15)] = v[k];
  __syncthreads();
#pragma unroll
  for (int k = 0; k < 16; k++) v[k] = lds[t * 17 + k];
  fwht16(v);
  const float cst = 1.0f / 2048.0f;
  union { unsigned short u[16]; uint4 q[2]; } o;
#pragma unroll
  for (int k = 0; k < 16; k++) o.u[k] = f2bf(v[k] * cst);
  uint4* dst = (uint4*)(H1 + row * 4096 + (size_t)t * 16);
  dst[0] = o.q[0];
  dst[1] = o.q[1];
}

// ---------------- W conversion: Wb[m][n] = bf16(W[m][n] * Wscale[m]) -------
__global__ __launch_bounds__(256) void convw_kernel(
    const float4* __restrict__ W4, const float* __restrict__ Wscale,
    uint2* __restrict__ Wb4, int total4, int Nq) {
  int i = blockIdx.x * 256 + threadIdx.x;
  if (i >= total4) return;
  float4 w = W4[i];
  float s = Wscale[i / Nq];
  unsigned int lo = (unsigned)f2bf(w.x * s) | ((unsigned)f2bf(w.y * s) << 16);
  unsigned int hi = (unsigned)f2bf(w.z * s) | ((unsigned)f2bf(w.w * s) << 16);
  Wb4[i] = make_uint2(lo, hi);
}

// ---------------- GEMM: 256x256, BK=64, 8 waves, balanced 8-phase ----------
// ds_reads 8/4/8/4 per phase (template's "4 or 8"): next K-tile's B-v0 is
// loaded in the v1-set's freed registers during the 0-read phase (roles of
// bvP/bvQ alternate statically per K-tile parity -> no extra VGPRs).
// A staged as read-matched regions R0={rows 0-63,128-191}, R1={64-127,
// 192-255} so each staged half has its own deadline. Stage 1 half/phase:
// P8':B0(b) P1:B1(b) P2:AR0(b) P3:AR1(b) P4:B0(c) ... deadlines (first read):
// B(b) @P4 (cross-buffer v0 read), AR0(b) @P5, AR1(b) @P7 -> slacks 3/2/2/3
// phases >= HBM latency. Counted gates (FIFO-verified, per wave, 2 loads per
// half): P2:v6 P3:v4 P4:v4 P6:v6 P7:v4 P8:v4; never 0 except tail.

#define BAR() __builtin_amdgcn_s_barrier()
#define SCHED() __builtin_amdgcn_sched_barrier(0)
#define GATE6()                              \
  do {                                       \
    SCHED();                                 \
    asm volatile("s_waitcnt vmcnt(6)");      \
    SCHED();                                 \
  } while (0)
#define GATE4()                              \
  do {                                       \
    SCHED();                                 \
    asm volatile("s_waitcnt vmcnt(4)");      \
    SCHED();                                 \
  } while (0)
#define GATE2()                              \
  do {                                       \
    SCHED();                                 \
    asm volatile("s_waitcnt vmcnt(2)");      \
    SCHED();                                 \
  } while (0)
#define GATE0()                              \
  do {                                       \
    SCHED();                                 \
    asm volatile("s_waitcnt vmcnt(0)");      \
    SCHED();                                 \
  } while (0)

// Stage A region h (h=0: global rows {0-63,128-191}; h=1: {64-127,192-255})
// of buf d <- K-tile kt. LDS dest linear; source pre-swizzled (chunk^=rl&7).
__device__ __forceinline__ void stage_A(const unsigned short* __restrict__ Ab,
                                        unsigned short* lr, int h, int kt,
                                        int tid, int K) {
#pragma unroll
  for (int i = 0; i < 2; i++) {
    int idx = i * 512 + tid;
    int rl = idx >> 3;  // region-local row 0..127
    int c = (idx & 7) ^ (rl & 7);
    int grow = (rl >> 6) * 128 + h * 64 + (rl & 63);
    gload16(Ab + (size_t)grow * K + (size_t)kt * 64 + c * 8, lr + idx * 8);
  }
}
// Stage B col-half hh (contiguous cols hh*128..+127) of buf d <- K-tile kt.
__device__ __forceinline__ void stage_B(const unsigned short* __restrict__ Bb,
                                        unsigned short* lr, int tid, int K) {
#pragma unroll
  for (int i = 0; i < 2; i++) {
    int idx = i * 512 + tid;
    int rl = idx >> 3;
    int c = (idx & 7) ^ (rl & 7);
    gload16(Bb + (size_t)rl * K + c * 8, lr + idx * 8);
  }
}

#define STAGE_A(d, h, kt) stage_A(Abase, &As[d][(h)*8192], (h), (kt), tid, K)
#define STAGE_B(d, hh, kt) \
  stage_B(Bbase + (size_t)(hh)*128 * K + (size_t)(kt)*64, &Bs[d][(hh)*8192], tid, K)

// Read A m-sub m of buf d (region m, region-local rows wm*64 .. +63) -> ah.
#define LOAD_A(d, m)                                                           \
  {                                                                            \
    _Pragma("unroll") for (int i = 0; i < 4; i++) {                            \
      _Pragma("unroll") for (int ks = 0; ks < 2; ks++) {                       \
        int rl = wm * 64 + i * 16 + fr;                                        \
        int kc = ks * 4 + lhi;                                                 \
        ah[i][ks] =                                                            \
            *(const bf16x8*)&As[d][(m)*8192 + rl * 64 + ((kc ^ (rl & 7)) << 3)]; \
      }                                                                        \
    }                                                                          \
  }

// Read B n-sub v of buf d (cols wn*64+v*32 .. +31, linear [256][64]) -> dst.
#define LOAD_B(d, v, dst)                                                     \
  {                                                                           \
    _Pragma("unroll") for (int j = 0; j < 2; j++) {                           \
      _Pragma("unroll") for (int ks = 0; ks < 2; ks++) {                      \
        int r = wn * 64 + (v)*32 + j * 16 + fr;                               \
        int kc = ks * 4 + lhi;                                                \
        dst[j][ks] = *(const bf16x8*)&Bs[d][r * 64 + ((kc ^ (r & 7)) << 3)];  \
      }                                                                       \
    }                                                                         \
  }

#define MFMA_PH(m, v, bvx)                                                    \
  {                                                                           \
    __builtin_amdgcn_s_setprio(1);                                            \
    _Pragma("unroll") for (int i = 0; i < 4; i++)                             \
      _Pragma("unroll") for (int j = 0; j < 2; j++)                           \
        _Pragma("unroll") for (int ks = 0; ks < 2; ks++)                      \
          acc[(m)*4 + i][(v)*2 + j] = __builtin_amdgcn_mfma_f32_16x16x32_bf16( \
              ah[i][ks], bvx[j][ks], acc[(m)*4 + i][(v)*2 + j], 0, 0, 0);     \
    __builtin_amdgcn_s_setprio(0);                                            \
  }

__global__ __launch_bounds__(512, 2) void gemm8_kernel(
    const unsigned short* __restrict__ A, const unsigned short* __restrict__ B,
    float* __restrict__ C, int M, int K, int NT) {
  __shared__ __align__(16) unsigned short As[2][256 * 64];
  __shared__ __align__(16) unsigned short Bs[2][256 * 64];
  const int nbn = M >> 8;
  const int cpx = gridDim.x >> 3;
  int bid = blockIdx.x;
  bid = (bid & 7) * cpx + (bid >> 3);  // XCD swizzle (grid % 8 == 0)
  const int brow = (bid / nbn) << 8;
  const int bcol = (bid % nbn) << 8;
  const int tid = threadIdx.x;
  const int lane = tid & 63;
  const int w = tid >> 6;  // 8 waves: 2 (M) x 4 (N)
  const int wm = w >> 2;
  const int wn = w & 3;
  const int fr = lane & 15;
  const int lhi = lane >> 4;

  const unsigned short* Abase = A + (size_t)brow * K;
  const unsigned short* Bbase = B + (size_t)bcol * K;

  f32x4 acc[8][4];
#pragma unroll
  for (int i = 0; i < 8; i++)
#pragma unroll
    for (int j = 0; j < 4; j++) acc[i][j] = (f32x4){0.f, 0.f, 0.f, 0.f};
  bf16x8 ah[4][2], bvP[2][2], bvQ[2][2];

  // Prologue: b0 <- tile0 (B0,B1,AR0,AR1 = 8 loads); b1.B0 <- tile1 (2).
  // GATE2: drain b0's 8, leave b1.B0 flying. Then preload bvP = tile0 v0.
  STAGE_B(0, 0, 0);
  STAGE_B(0, 1, 0);
  STAGE_A(0, 0, 0);
  STAGE_A(0, 1, 0);
  STAGE_B(1, 0, 1);
  GATE2();
  BAR();
  LOAD_B(0, 0, bvP);

  const int NTT = NT / 2;
#pragma unroll 1
  for (int t = 0; t < NTT; ++t) {
    const bool last = (t == NTT - 1);
    const int u1 = 2 * t + 1, u2 = 2 * t + 2, u3 = 2 * t + 3;
    // P1: dsr A(b0)R0 [8]; stage b1.B1<-u1
    LOAD_A(0, 0);
    STAGE_B(1, 1, u1);
    BAR();
    MFMA_PH(0, 0, bvP);
    BAR();
    // P2: dsr B(b0)v1->bvQ [4]; stage b1.AR0<-u1; gate prev AR1 (t=0: no-op)
    LOAD_B(0, 1, bvQ);
    STAGE_A(1, 0, u1);
    BAR();
    MFMA_PH(0, 1, bvQ);
    GATE6();
    BAR();
    // P3: dsr A(b0)R1 [8]; stage b1.AR1<-u1; gate b1's B halves (for P4)
    LOAD_A(0, 1);
    STAGE_A(1, 1, u1);
    BAR();
    MFMA_PH(1, 1, bvQ);
    GATE4();
    BAR();
    // P4: dsr B(b1)v0->bvQ [4] (cross-buffer); stage b0.B0<-u2;
    //     gate b1.AR0 (for P5)
    LOAD_B(1, 0, bvQ);
    if (!last) STAGE_B(0, 0, u2);
    BAR();
    MFMA_PH(1, 0, bvP);
    if (!last) { GATE4(); } else { GATE0(); }
    BAR();
    // P5: dsr A(b1)R0 [8]; stage b0.B1<-u2
    LOAD_A(1, 0);
    if (!last) STAGE_B(0, 1, u2);
    BAR();
    MFMA_PH(0, 0, bvQ);
    BAR();
    // P6: dsr B(b1)v1->bvP [4]; stage b0.AR0<-u2; gate b1.AR1 (for P7)
    LOAD_B(1, 1, bvP);
    if (!last) STAGE_A(0, 0, u2);
    BAR();
    MFMA_PH(0, 1, bvP);
    if (!last) GATE6();
    BAR();
    // P7: dsr A(b1)R1 [8]; stage b0.AR1<-u2; gate b0's B halves (for P8)
    LOAD_A(1, 1);
    if (!last) STAGE_A(0, 1, u2);
    BAR();
    MFMA_PH(1, 1, bvP);
    if (!last) GATE4();
    BAR();
    // P8: dsr B(b0)v0->bvP [4] (tile u2; stale+dead in tail); stage
    //     b1.B0<-u3; gate b0.AR0 (for P1')
    LOAD_B(0, 0, bvP);
    if (!last) STAGE_B(1, 0, u3);
    BAR();
    MFMA_PH(1, 0, bvQ);
    if (!last) GATE4();
    BAR();
  }

  // Epilogue: C/D layout col=lane&15, row=(lane>>4)*4+q  [m89-verified]
  const int crow0 = brow + wm * 128 + lhi * 4;
  const int ccol0 = bcol + wn * 64 + fr;
#pragma unroll
  for (int mi = 0; mi < 8; mi++)
#pragma unroll
    for (int nj = 0; nj < 4; nj++)
#pragma unroll
      for (int q = 0; q < 4; q++)
        C[(size_t)(crow0 + mi * 16 + q) * M + ccol0 + nj * 16] = acc[mi][nj][q];
}

// ---------------- FWHT #2 (in-place on d_out): out = fwht(Y)*0.5*SV ------
__global__ __launch_bounds__(256) void fwht2_kernel(
    float* __restrict__ Y, const float* __restrict__ SV) {
  __shared__ float lds[256 * 17];
  const int t = threadIdx.x;
  const size_t row = blockIdx.x;
  float* yr = Y + row * 4096;
  float v[16];
#pragma unroll
  for (int n2 = 0; n2 < 16; n2++) v[n2] = yr[n2 * 256 + t];
  fwht16(v);
  const int n1 = t >> 4, n0 = t & 15;
#pragma unroll
  for (int j2 = 0; j2 < 16; j2++) lds[(j2 * 16 + n1) * 17 + n0] = v[j2];
  __syncthreads();
#pragma unroll
  for (int k = 0; k < 16; k++) v[k] = lds[((t >> 4) * 16 + k) * 17 + (t & 15)];
  fwht16(v);
#pragma unroll
  for (int k = 0; k < 16; k++) lds[((t >> 4) * 16 + k) * 17 + (t & 15)] = v[k];
  __syncthreads();
#pragma unroll
  for (int k = 0; k < 16; k++) v[k] = lds[t * 17 + k];
  fwht16(v);
  float outv[16];
#pragma unroll
  for (int k = 0; k < 16; k++) outv[k] = v[k] * 0.5f * SV[(size_t)t * 16 + k];
  float4* dst = (float4*)(yr + (size_t)t * 16);
#pragma unroll
  for (int k = 0; k < 4; k++)
    dst[k] = make_float4(outv[4 * k], outv[4 * k + 1], outv[4 * k + 2],
                         outv[4 * k + 3]);
}

extern "C" void kernel_launch(void* const* d_in, const int* in_sizes, int n_in,
                              void* d_out, int out_size, void* d_ws,
                              size_t ws_size, hipStream_t stream) {
  const float* x = (const float*)d_in[0];
  const float* W = (const float*)d_in[1];
  const float* SU = (const float*)d_in[2];
  const float* SV = (const float*)d_in[3];
  const float* Wscale = (const float*)d_in[4];
  const int N = in_sizes[2];      // 4096
  const int M = in_sizes[3];      // 4096
  const int T = in_sizes[0] / N;  // 16384

  unsigned short* H1 = (unsigned short*)d_ws;
  unsigned short* Wb = H1 + (size_t)T * N;
  float* out = (float*)d_out;

  fwht1_kernel<<<T, 256, 0, stream>>>(x, SU, H1);
  const int total4 = (int)(((long)M * N) / 4);
  convw_kernel<<<(total4 + 255) / 256, 256, 0, stream>>>(
      (const float4*)W, Wscale, (uint2*)Wb, total4, N / 4);
  const int NT = N / 64;  // 64 K-tiles
  gemm8_kernel<<<(T / 256) * (M / 256), 512, 0, stream>>>(H1, Wb, out, M, N, NT);
  fwht2_kernel<<<T, 256, 0, stream>>>(out, SV);
}